// Round 2
// baseline (845.880 us; speedup 1.0000x reference)
//
#include <hip/hip_runtime.h>

// BlockDense: out[b, g*16+h] = relu( sum_w x[b, g*16+w] * W[g, w, h] )
// B=8192, G=1024, w=16, H=16, fp32. Memory-bound: 1.07 GB -> ~170us floor @6.3TB/s.
//
// LDS-free design:
//  - wave owns a 16-group panel (1 KiB/row = 64 lanes x float4): lane l ->
//    group gl=l>>2, h-quad h4=l&3.
//  - W[g][w][h4*4..+4] kept in registers (16 x float4 = 64 VGPR), loaded once
//    per block; W is 1 MiB total -> L2-resident across the 128 row-tiles.
//  - per row: 1 coalesced dwordx4 load, 16 v_mov_dpp quad-perm broadcasts
//    (VALU pipe, no LDS), 64 FMA, relu, 1 coalesced dwordx4 store.
//  - zero LDS, zero barriers -> no vmcnt(0) drain points; 1-row prefetch +
//    4 blocks/CU hide HBM latency.

constexpr int Bv   = 8192;
constexpr int COLS = 16384;        // G*16
constexpr int GT   = 16;           // groups per block tile (one wave-width panel)
constexpr int RPW  = 16;           // rows per wave
constexpr int BT   = 4 * RPW;      // 64 rows per block (4 waves)

template <int CTRL>
__device__ __forceinline__ float4 quad_bcast(float4 v) {
    // DPP quad_perm broadcast of quad-lane J (CTRL = J*0x55). Pure VALU.
    float4 r;
    r.x = __int_as_float(__builtin_amdgcn_update_dpp(0, __float_as_int(v.x), CTRL, 0xF, 0xF, true));
    r.y = __int_as_float(__builtin_amdgcn_update_dpp(0, __float_as_int(v.y), CTRL, 0xF, 0xF, true));
    r.z = __int_as_float(__builtin_amdgcn_update_dpp(0, __float_as_int(v.z), CTRL, 0xF, 0xF, true));
    r.w = __int_as_float(__builtin_amdgcn_update_dpp(0, __float_as_int(v.w), CTRL, 0xF, 0xF, true));
    return r;
}

__global__ __launch_bounds__(256, 4)
void block_dense_kernel(const float* __restrict__ x,
                        const float* __restrict__ W,
                        float* __restrict__ out) {
    const int t    = threadIdx.x;
    const int lane = t & 63;
    const int wv   = t >> 6;
    const int gl   = lane >> 2;     // group within tile (0..15)
    const int h4   = lane & 3;      // h-quad within group (0..3)

    const int gtile = blockIdx.x;                    // 0..63
    const int b0    = blockIdx.y * BT + wv * RPW;    // this wave's first row

    // ---- W panel -> registers: lane holds W[g][w][h4*4 .. +4] for w=0..15 ----
    float4 wr[16];
    {
        const float* wb = W + (size_t)(gtile * GT + gl) * 256 + h4 * 4;
        #pragma unroll
        for (int w = 0; w < 16; ++w)
            wr[w] = *reinterpret_cast<const float4*>(wb + w * 16);
    }

    // ---- row loop: coalesced 1KiB/wave load, DPP fan-out, FMA, coalesced store ----
    const size_t off = (size_t)b0 * COLS + (size_t)gtile * (GT * 16) + lane * 4;
    const float* xp = x + off;
    float*       op = out + off;

    float4 cur = *reinterpret_cast<const float4*>(xp);
    #pragma unroll
    for (int i = 0; i < RPW; ++i) {
        float4 nxt = {0.f, 0.f, 0.f, 0.f};
        if (i + 1 < RPW)
            nxt = *reinterpret_cast<const float4*>(xp + (size_t)(i + 1) * COLS);

        // quad collectively holds this group's 16 x values; broadcast each
        // quad-lane's float4 to the whole quad (16 v_mov_dpp total).
        const float4 q0 = quad_bcast<0x00>(cur);
        const float4 q1 = quad_bcast<0x55>(cur);
        const float4 q2 = quad_bcast<0xAA>(cur);
        const float4 q3 = quad_bcast<0xFF>(cur);
        const float xs16[16] = {q0.x, q0.y, q0.z, q0.w,
                                q1.x, q1.y, q1.z, q1.w,
                                q2.x, q2.y, q2.z, q2.w,
                                q3.x, q3.y, q3.z, q3.w};

        float4 acc = {0.f, 0.f, 0.f, 0.f};
        #pragma unroll
        for (int w = 0; w < 16; ++w) {
            acc.x = fmaf(xs16[w], wr[w].x, acc.x);
            acc.y = fmaf(xs16[w], wr[w].y, acc.y);
            acc.z = fmaf(xs16[w], wr[w].z, acc.z);
            acc.w = fmaf(xs16[w], wr[w].w, acc.w);
        }
        acc.x = fmaxf(acc.x, 0.f);
        acc.y = fmaxf(acc.y, 0.f);
        acc.z = fmaxf(acc.z, 0.f);
        acc.w = fmaxf(acc.w, 0.f);

        *reinterpret_cast<float4*>(op + (size_t)i * COLS) = acc;
        cur = nxt;
    }
}

extern "C" void kernel_launch(void* const* d_in, const int* in_sizes, int n_in,
                              void* d_out, int out_size, void* d_ws, size_t ws_size,
                              hipStream_t stream) {
    const float* x = (const float*)d_in[0];   // (8192, 16384) fp32
    const float* W = (const float*)d_in[1];   // (1024, 16, 16) fp32
    float* out = (float*)d_out;               // (8192, 16384) fp32

    dim3 grid(COLS / (GT * 16), Bv / BT);     // (64, 128)
    dim3 block(256);
    block_dense_kernel<<<grid, block, 0, stream>>>(x, W, out);
}